// Round 15
// baseline (279.956 us; speedup 1.0000x reference)
//
#include <hip/hip_runtime.h>

#define NC 64      // channels / signal dim
#define NA 512     // dictionary atoms
#define KS 5       // sparsity

// ---- workspace layout in DOUBLES ----
#define WS_DN   0        // Dn_f64 [NC][NA]   (for gram)
#define WS_DNT  32768    // DnT    [NA][NC]   (for epilogue reconstruction)
#define WS_G    65536    // G      [NA][NA]
#define WS_RDEN 327680   // 1/den  [NA]
#define WS_ACC  328192   // loss accumulator

// out layout (FLOAT32): z_dl[2097152] | loss[1] | support[163840] | coeffs[163840]
#define OUT_LOSS 2097152
#define OUT_SUP  2097153
#define OUT_COF  2260993

__global__ void norm_kernel(const float* __restrict__ D, double* __restrict__ Dn,
                            double* __restrict__ DnT, double* __restrict__ rden) {
  int n = blockIdx.x * blockDim.x + threadIdx.x;
  if (n >= NA) return;
  double s = 0.0;
  for (int c = 0; c < NC; ++c) {
    double v = (double)D[c * NA + n];
    s += v * v;
  }
  double dd = fmax(sqrt(s), 1e-10);
  rden[n] = 1.0 / dd;
  for (int c = 0; c < NC; ++c) {
    double v = (double)D[c * NA + n] / dd;
    Dn[c * NA + n]  = v;
    DnT[n * NC + c] = v;
  }
}

__global__ void gram_kernel(const double* __restrict__ Dn,
                            double* __restrict__ G, double* __restrict__ accum) {
  __shared__ double col[NC];
  int i = blockIdx.x, t = threadIdx.x;
  if (t < NC) col[t] = Dn[t * NA + i];
  if (i == 0 && t == 0) *accum = 0.0;
  __syncthreads();
  double s = 0.0;
#pragma unroll
  for (int c = 0; c < NC; ++c) s += col[c] * Dn[c * NA + t];
  G[(size_t)i * NA + t] = s;
}

// One OMP iteration, compile-time KK. Half-wave = one signal (q = lane&31).
// h lives in LDS (in-place incremental update): spill-safe like R12.
// hbI reconstructed: h_run[idx] + sum_{j<KK} gamp[j]*Gc[j]  (R14-verified).
// Lane q owns atom pairs: slot (i,p) <-> atom a = i*64 + 2*q + p, i=0..7.
template<int KK>
__device__ __forceinline__ void omp_step(
    const int q, const double* __restrict__ G,
    double* __restrict__ hL,          // my signal's running h in LDS (512 f64)
    unsigned &msk, int (&I)[KS],
    double (&Lm)[15], double (&rd)[KS], double (&gam)[KS],
    double (&gamp)[KS], double (&hbI)[KS]) {
  double2* h2 = (double2*)hL;
  // argmax |h|*mask, streaming (ascending atoms + strict '>' = first-occurrence)
  double bv = -1.0; int bn = 0;
#pragma unroll
  for (int i = 0; i < 8; ++i) {
    double2 hv = h2[i * 32 + q];
    const int a0 = i * 64 + 2 * q;
    double v0 = ((msk >> (2 * i)) & 1u)     ? fabs(hv.x) : 0.0;
    double v1 = ((msk >> (2 * i + 1)) & 1u) ? fabs(hv.y) : 0.0;
    if (v0 > bv) { bv = v0; bn = a0; }
    if (v1 > bv) { bv = v1; bn = a0 + 1; }
  }
#pragma unroll
  for (int off = 1; off < 32; off <<= 1) {   // butterfly within the 32-lane half
    double ov = __shfl_xor(bv, off);
    int    on = __shfl_xor(bn, off);
    if (ov > bv || (ov == bv && on < bn)) { bv = ov; bn = on; }
  }
  const int idx = bn;                        // uniform within the half
  if (((idx & 63) >> 1) == q)
    msk &= ~(1u << (((idx >> 6) << 1) | (idx & 1)));
  I[KK] = idx;

  const double hsel = hL[idx];               // LDS broadcast read (per half)

  // Cholesky update + hbI reconstruction (replicated within the half)
  if constexpr (KK == 0) {
    hbI[0] = hsel;
    Lm[0] = 1.0; rd[0] = 1.0;
  } else {
    double Gc[KK], w_[KK];
#pragma unroll
    for (int j = 0; j < KK; ++j) Gc[j] = G[(size_t)I[j] * NA + idx];
    double corr = 0.0;
#pragma unroll
    for (int j = 0; j < KK; ++j) corr += gamp[j] * Gc[j];
    hbI[KK] = hsel + corr;                   // reconstructed h_bar[idx]
#pragma unroll
    for (int i = 0; i < KK; ++i) {
      double ssum = Gc[i];
#pragma unroll
      for (int j = 0; j < i; ++j) ssum -= Lm[i*(i+1)/2 + j] * w_[j];
      w_[i] = ssum * rd[i];
    }
    double ww = 0.0;
#pragma unroll
    for (int i = 0; i < KK; ++i) ww += w_[i] * w_[i];
    double corner = sqrt(fmax(1.0 - ww, 1e-12));
#pragma unroll
    for (int j = 0; j < KK; ++j) Lm[KK*(KK+1)/2 + j] = w_[j];
    Lm[KK*(KK+1)/2 + KK] = corner;
    rd[KK] = 1.0 / corner;
  }

  // gamma = cho_solve((L, lower), h_bar[I]) at size KK+1
  double y[KK + 1];
#pragma unroll
  for (int i = 0; i <= KK; ++i) {
    double b_ = hbI[i];
#pragma unroll
    for (int j = 0; j < i; ++j) b_ -= Lm[i*(i+1)/2 + j] * y[j];
    y[i] = b_ * rd[i];
  }
#pragma unroll
  for (int i = KK; i >= 0; --i) {
    double g_ = y[i];
#pragma unroll
    for (int j = i + 1; j <= KK; ++j) g_ -= Lm[j*(j+1)/2 + i] * gam[j];
    gam[i] = g_ * rd[i];
  }

  // incremental in-place h-update in LDS: h -= sum_j (gam_j - gamp_j)*G[I_j]
  if constexpr (KK < 4) {
    double dg[KK + 1];
#pragma unroll
    for (int j = 0; j <= KK; ++j) {
      dg[j] = gam[j] - ((j < KK) ? gamp[j] : 0.0);
      gamp[j] = gam[j];
    }
#pragma unroll
    for (int i = 0; i < 8; ++i) {
      double2 hv = h2[i * 32 + q];
#pragma unroll
      for (int j = 0; j <= KK; ++j) {
        double2 g = ((const double2*)(G + (size_t)I[j] * NA))[i * 32 + q];
        hv.x -= dg[j] * g.x;
        hv.y -= dg[j] * g.y;
      }
      h2[i * 32 + q] = hv;
    }
  }
}

union __align__(16) StageBuf {
  float  f[8 * NA];    // 16 KB view: f32 D-chunk staging (phase 1)
  double d[8 * NA];    // 32 KB view: running h[8][512]   (phase 2)
};

// 8 signals per block: 4 waves x 2 half-waves, one signal per 32-lane half.
// Grid 4096. Both signals of a wave run in the SAME instructions (SIMT).
__global__ __launch_bounds__(256, 2) void omp_kernel(
    const float* __restrict__ z, const float* __restrict__ Draw,
    const double* __restrict__ DnT, const double* __restrict__ G,
    const double* __restrict__ rden, float* __restrict__ out,
    double* __restrict__ accum) {
  __shared__ StageBuf buf;
  __shared__ float xsz[8 * NC];      // 2 KB: xs[s][c] first, zout[c][s] later
  __shared__ double wsq[8];
  const int t = threadIdx.x, lane = t & 63, wv = t >> 6;
  const int q = lane & 31;                 // lane within half
  const int mysig = wv * 2 + (lane >> 5);  // this half's signal (0..7)
  const int m0 = blockIdx.x * 8;
  const int bh = m0 >> 6, b = bh >> 6, h = bh & 63, w0 = m0 & 63;
  const size_t zbase = (size_t)b * 262144 + (size_t)h * 64 + w0;

  // load 8 signals coalesced into xs (xsz[s*64+c])
  for (int j = t; j < 8 * NC; j += 256) {
    int c = j >> 3, s = j & 7;
    xsz[s * NC + c] = z[zbase + (size_t)c * 4096 + s];
  }
  __syncthreads();
  // hoist this half's two epilogue channels into regs (xsz reused as zout later)
  const float e0f  = xsz[mysig * NC + q];
  const float e32f = xsz[mysig * NC + q + 32];

  // ---- phase 1: h_bar GEMM. acc_f64 += f64(x_f32)*f64(D_f32) (exact);
  //      scaled by 1/den at LDS park. Lane: 16 slots of ONE signal.
  {
    double acc[16];
#pragma unroll
    for (int i = 0; i < 16; ++i) acc[i] = 0.0;

    const float4* D4 = (const float4*)Draw;
    float4* st4 = (float4*)buf.f;
    for (int ch = 0; ch < 8; ++ch) {
      if (ch) __syncthreads();             // previous chunk fully consumed
#pragma unroll
      for (int p = 0; p < 4; ++p)          // 1024 float4 per 8-row chunk
        st4[p * 256 + t] = D4[ch * 1024 + p * 256 + t];
      __syncthreads();
#pragma unroll
      for (int c8 = 0; c8 < 8; ++c8) {
        const int c = ch * 8 + c8;
        const double xv = (double)xsz[mysig * NC + c];  // LDS broadcast per half
        const float2* row2 = (const float2*)(buf.f + c8 * NA);
#pragma unroll
        for (int i = 0; i < 8; ++i) {
          float2 dv = row2[i * 32 + q];    // same addr both halves -> broadcast
          acc[i * 2]     += xv * (double)dv.x;
          acc[i * 2 + 1] += xv * (double)dv.y;
        }
      }
    }
    __syncthreads();                       // all waves done with f32 stage
    // park h_bar (scaled by 1/den) into LDS f64 view; acc DIES here
    double2* myh2 = (double2*)(buf.d + (size_t)mysig * NA);
#pragma unroll
    for (int i = 0; i < 8; ++i) {
      double2 r2 = ((const double2*)rden)[i * 32 + q];
      double2 v;
      v.x = acc[i * 2]     * r2.x;
      v.y = acc[i * 2 + 1] * r2.y;
      myh2[i * 32 + q] = v;
    }
  }

  // ---- phase 2: OMP, one signal per half-wave, single pass of 5 steps
  double* hL = buf.d + (size_t)mysig * NA;
  const int m = m0 + mysig;
  unsigned msk = 0xFFFFu;                  // 16 slots per lane
  int I[KS];
  double Lm[15], rd[KS], gam[KS], gamp[KS], hbI[KS];

  omp_step<0>(q, G, hL, msk, I, Lm, rd, gam, gamp, hbI);
  omp_step<1>(q, G, hL, msk, I, Lm, rd, gam, gamp, hbI);
  omp_step<2>(q, G, hL, msk, I, Lm, rd, gam, gamp, hbI);
  omp_step<3>(q, G, hL, msk, I, Lm, rd, gam, gamp, hbI);
  omp_step<4>(q, G, hL, msk, I, Lm, rd, gam, gamp, hbI);

  // ---- epilogue: lane covers channels q and q+32 of its signal
  double r0 = 0.0, r32 = 0.0;
#pragma unroll
  for (int j = 0; j < KS; ++j) {
    const double* dn = DnT + (size_t)I[j] * NC;
    r0  += gam[j] * dn[q];
    r32 += gam[j] * dn[q + 32];
  }
  const double d0  = r0  - (double)e0f;    // z_dl - z_e
  const double d32 = r32 - (double)e32f;
  xsz[q * 8 + mysig]        = (float)((double)e0f  + d0);   // zout[c][s]
  xsz[(q + 32) * 8 + mysig] = (float)((double)e32f + d32);
  double sq = d0 * d0 + d32 * d32;
#pragma unroll
  for (int off = 1; off < 32; off <<= 1) sq += __shfl_xor(sq, off);
  if (q == 0) wsq[mysig] = sq;

  // support / coeffs: constant-index selection chains only
  if (q < KS) {
    int    iv = I[0];
    double gv = gam[0];
    if (q == 1) { iv = I[1]; gv = gam[1]; }
    if (q == 2) { iv = I[2]; gv = gam[2]; }
    if (q == 3) { iv = I[3]; gv = gam[3]; }
    if (q == 4) { iv = I[4]; gv = gam[4]; }
    out[OUT_SUP + (size_t)m * KS + q] = (float)iv;
    out[OUT_COF + (size_t)m * KS + q] = (float)gv;
  }

  __syncthreads();
  // coalesced z_dl store from zout (xsz[c*8+s])
  for (int j = t; j < 8 * NC; j += 256) {
    int c = j >> 3, s = j & 7;
    out[zbase + (size_t)c * 4096 + s] = xsz[j];
  }
  if (t == 0) {
    double ssum = 0.0;
#pragma unroll
    for (int i = 0; i < 8; ++i) ssum += wsq[i];
    atomicAdd(accum, ssum);
  }
}

__global__ void final_kernel(const double* __restrict__ accum, float* __restrict__ out) {
  double mse = *accum / 2097152.0;
  out[OUT_LOSS] = (float)(mse + 0.25 * mse);
}

extern "C" void kernel_launch(void* const* d_in, const int* in_sizes, int n_in,
                              void* d_out, int out_size, void* d_ws, size_t ws_size,
                              hipStream_t stream) {
  const float* z_e = (const float*)d_in[0];
  const float* dic = (const float*)d_in[1];
  float* out = (float*)d_out;
  double* ws = (double*)d_ws;
  double* Dn   = ws + WS_DN;
  double* DnT  = ws + WS_DNT;
  double* G    = ws + WS_G;
  double* rden = ws + WS_RDEN;
  double* accu = ws + WS_ACC;

  hipLaunchKernelGGL(norm_kernel,  dim3(1),    dim3(512), 0, stream, dic, Dn, DnT, rden);
  hipLaunchKernelGGL(gram_kernel,  dim3(NA),   dim3(NA),  0, stream, Dn, G, accu);
  hipLaunchKernelGGL(omp_kernel,   dim3(4096), dim3(256), 0, stream,
                     z_e, dic, DnT, G, rden, out, accu);
  hipLaunchKernelGGL(final_kernel, dim3(1),    dim3(1),   0, stream, accu, out);
}

// Round 16
// 195.365 us; speedup vs baseline: 1.4330x; 1.4330x over previous
//
#include <hip/hip_runtime.h>

#define NC 64      // channels / signal dim
#define NA 512     // dictionary atoms
#define KS 5       // sparsity

// ---- workspace layout in FLOATS (accum as double at 8B-aligned tail) ----
#define WS_DN   0        // Dn  [NC][NA]
#define WS_DNT  32768    // DnT [NA][NC]
#define WS_G    65536    // G   [NA][NA]
#define WS_ACCF 327680   // double accumulator lives here (byte off 1310720)

// out layout (FLOAT32): z_dl[2097152] | loss[1] | support[163840] | coeffs[163840]
#define OUT_LOSS 2097152
#define OUT_SUP  2097153
#define OUT_COF  2260993

__global__ void norm_kernel(const float* __restrict__ D, float* __restrict__ Dn,
                            float* __restrict__ DnT) {
  int n = blockIdx.x * 64 + threadIdx.x;
  float s = 0.f;
  for (int c = 0; c < NC; ++c) {
    float v = D[c * NA + n];
    s += v * v;
  }
  float den = fmaxf(sqrtf(s), 1e-10f);
  for (int c = 0; c < NC; ++c) {
    float v = D[c * NA + n] / den;      // f32 true division, mirrors ref
    Dn[c * NA + n]  = v;
    DnT[n * NC + c] = v;
  }
}

__global__ void gram_kernel(const float* __restrict__ Dn,
                            float* __restrict__ G, double* __restrict__ accum) {
  __shared__ float col[NC];
  int i = blockIdx.x, t = threadIdx.x;
  if (t < NC) col[t] = Dn[t * NA + i];
  if (i == 0 && t == 0) *accum = 0.0;
  __syncthreads();
  float s = 0.f;
#pragma unroll
  for (int c = 0; c < NC; ++c) s += col[c] * Dn[c * NA + t];
  G[(size_t)i * NA + t] = s;
}

// One OMP iteration, compile-time KK (all private indices literal -> SROA
// keeps state in VGPRs; h_bar parked in LDS -- the R12-proven spill-safe
// pattern). All f32 (selection-safety established empirically: f64-vs-f32ref
// showed zero support flips in 163840 draws).
// Lane owns atom pairs: slot s (0..7) <-> atom a = (s>>1)*128 + 2*lane + (s&1).
template<int KK>
__device__ __forceinline__ void omp_step(
    const int lane, const float* __restrict__ G,
    const float* __restrict__ hbs, const float2* __restrict__ hb2,
    float (&h8)[8], unsigned &msk, int (&I)[KS],
    float (&Lm)[15], float (&rd)[KS], float (&gam)[KS], float (&hbI)[KS]) {
  // argmax |h|*mask; ascending-atom scan with strict '>' = first-occurrence
  float bv = -1.f; int bn = 0;
#pragma unroll
  for (int s = 0; s < 8; ++s) {
    int a = ((s >> 1) << 7) + 2 * lane + (s & 1);
    float v = ((msk >> s) & 1u) ? fabsf(h8[s]) : 0.f;
    if (v > bv) { bv = v; bn = a; }
  }
#pragma unroll
  for (int off = 1; off < 64; off <<= 1) {
    float ov = __shfl_xor(bv, off);
    int   on = __shfl_xor(bn, off);
    if (ov > bv || (ov == bv && on < bn)) { bv = ov; bn = on; }
  }
  const int idx = bn;                              // wave-uniform
  if (((idx & 127) >> 1) == lane)
    msk &= ~(1u << (((idx >> 7) << 1) | (idx & 1)));

  hbI[KK] = hbs[idx];                              // LDS broadcast read
  I[KK] = idx;

  // Cholesky update (replicated on all lanes; reciprocal-diag solves)
  if constexpr (KK == 0) {
    Lm[0] = 1.f; rd[0] = 1.f;
  } else {
    float Gc[KK], w_[KK];
#pragma unroll
    for (int j = 0; j < KK; ++j) Gc[j] = G[(size_t)I[j] * NA + idx];
#pragma unroll
    for (int i = 0; i < KK; ++i) {
      float ssum = Gc[i];
#pragma unroll
      for (int j = 0; j < i; ++j) ssum -= Lm[i*(i+1)/2 + j] * w_[j];
      w_[i] = ssum * rd[i];
    }
    float ww = 0.f;
#pragma unroll
    for (int i = 0; i < KK; ++i) ww += w_[i] * w_[i];
    float corner = sqrtf(fmaxf(1.f - ww, 1e-12f));
#pragma unroll
    for (int j = 0; j < KK; ++j) Lm[KK*(KK+1)/2 + j] = w_[j];
    Lm[KK*(KK+1)/2 + KK] = corner;
    rd[KK] = 1.f / corner;
  }

  // gamma = cho_solve((L, lower), h_bar[I]) at size KK+1
  float y[KK + 1];
#pragma unroll
  for (int i = 0; i <= KK; ++i) {
    float b_ = hbI[i];
#pragma unroll
    for (int j = 0; j < i; ++j) b_ -= Lm[i*(i+1)/2 + j] * y[j];
    y[i] = b_ * rd[i];
  }
#pragma unroll
  for (int i = KK; i >= 0; --i) {
    float g_ = y[i];
#pragma unroll
    for (int j = i + 1; j <= KK; ++j) g_ -= Lm[j*(j+1)/2 + i] * gam[j];
    gam[i] = g_ * rd[i];
  }

  // h = h_bar - sum_j gam_j * G[I_j]  (base from LDS park, rows from L2)
  if constexpr (KK < 4) {
#pragma unroll
    for (int i = 0; i < 4; ++i) {
      float2 hv = hb2[(i << 6) + lane];
      h8[i * 2] = hv.x; h8[i * 2 + 1] = hv.y;
    }
#pragma unroll
    for (int j = 0; j <= KK; ++j) {
      const float2* g2 = (const float2*)(G + (size_t)I[j] * NA);
      const float gj = gam[j];
#pragma unroll
      for (int i = 0; i < 4; ++i) {
        float2 g = g2[(i << 6) + lane];
        h8[i * 2]     -= gj * g.x;
        h8[i * 2 + 1] -= gj * g.y;
      }
    }
  }
}

// 8 signals per block (2 per wave), grid 4096.
// LDS: 16 KB stage/park union + 2 KB xsz -> ~18.4 KB -> 8 blocks/CU by LDS;
// f32 state ~60 VGPR -> 8 waves/SIMD. 2x R12's TLP for the latency chains.
__global__ __launch_bounds__(256, 2) void omp_kernel(
    const float* __restrict__ z, const float* __restrict__ Dn,
    const float* __restrict__ DnT, const float* __restrict__ G,
    float* __restrict__ out, double* __restrict__ accum) {
  __shared__ __align__(16) float buf[8 * NA];  // 16 KB: Dn stage, then h_bar park
  __shared__ float xsz[8 * NC];      // 2 KB: xs[s][c] first, zout[c][s] later
  __shared__ double wsq[8];
  const int t = threadIdx.x, lane = t & 63, wv = t >> 6;
  const int m0 = blockIdx.x * 8;
  const int bh = m0 >> 6, b = bh >> 6, h = bh & 63, w0 = m0 & 63;
  const size_t zbase = (size_t)b * 262144 + (size_t)h * 64 + w0;

  // load 8 signals coalesced into xs (xsz[s*64+c])
  for (int j = t; j < 8 * NC; j += 256) {
    int c = j >> 3, s = j & 7;
    xsz[s * NC + c] = z[zbase + (size_t)c * 4096 + s];
  }
  __syncthreads();
  // per-lane copy: lane holds channel=lane value of its wave's two signals
  const float xf0 = xsz[(wv * 2 + 0) * NC + lane];
  const float xf1 = xsz[(wv * 2 + 1) * NC + lane];
  // xsz free from here (zout reuses it)

  // ---- phase 1: f32 h_bar GEMM, Dn staged through LDS in 8-row chunks
  {
    float acc[2][8];
#pragma unroll
    for (int s = 0; s < 2; ++s)
#pragma unroll
      for (int i = 0; i < 8; ++i) acc[s][i] = 0.f;

    const float4* D4 = (const float4*)Dn;
    float4* st4 = (float4*)buf;
    for (int ch = 0; ch < 8; ++ch) {
      if (ch) __syncthreads();             // previous chunk fully consumed
#pragma unroll
      for (int p = 0; p < 4; ++p)          // 1024 float4 per 8-row chunk
        st4[p * 256 + t] = D4[ch * 1024 + p * 256 + t];
      __syncthreads();
#pragma unroll
      for (int c8 = 0; c8 < 8; ++c8) {
        const int c = ch * 8 + c8;
        const float x0 = __shfl(xf0, c);
        const float x1 = __shfl(xf1, c);
        const float2* row2 = (const float2*)(buf + c8 * NA);
#pragma unroll
        for (int i = 0; i < 4; ++i) {
          float2 dv = row2[(i << 6) + lane];
          acc[0][i * 2] += x0 * dv.x; acc[0][i * 2 + 1] += x0 * dv.y;
          acc[1][i * 2] += x1 * dv.x; acc[1][i * 2 + 1] += x1 * dv.y;
        }
      }
    }
    __syncthreads();                       // all waves done reading stage
    // park h_bar into the same 16 KB (per-wave region); acc DIES here
    float2* park2 = (float2*)buf;
#pragma unroll
    for (int si = 0; si < 2; ++si)
#pragma unroll
      for (int i = 0; i < 4; ++i) {
        float2 v; v.x = acc[si][i * 2]; v.y = acc[si][i * 2 + 1];
        park2[(size_t)(wv * 2 + si) * 256 + (i << 6) + lane] = v;
      }
  }

  // ---- phase 2: OMP, one wave per signal (2 sequential per wave)
#pragma unroll
  for (int si = 0; si < 2; ++si) {
    const int sig = wv * 2 + si, m = m0 + sig;
    const float*  hbs = buf + (size_t)sig * NA;              // parked h_bar
    const float2* hb2 = (const float2*)buf + (size_t)sig * 256;
    float h8[8];
#pragma unroll
    for (int i = 0; i < 4; ++i) {          // h(0) = h_bar, from LDS
      float2 hv = hb2[(i << 6) + lane];
      h8[i * 2] = hv.x; h8[i * 2 + 1] = hv.y;
    }
    unsigned msk = 0xFFu;
    int I[KS];
    float Lm[15], rd[KS], gam[KS], hbI[KS];

    omp_step<0>(lane, G, hbs, hb2, h8, msk, I, Lm, rd, gam, hbI);
    omp_step<1>(lane, G, hbs, hb2, h8, msk, I, Lm, rd, gam, hbI);
    omp_step<2>(lane, G, hbs, hb2, h8, msk, I, Lm, rd, gam, hbI);
    omp_step<3>(lane, G, hbs, hb2, h8, msk, I, Lm, rd, gam, hbI);
    omp_step<4>(lane, G, hbs, hb2, h8, msk, I, Lm, rd, gam, hbI);

    // ---- epilogue for this signal
    float r = 0.f;
#pragma unroll
    for (int j = 0; j < KS; ++j) r += gam[j] * DnT[(size_t)I[j] * NC + lane];
    const float e = (si == 0) ? xf0 : xf1;
    const float d = r - e;                       // z_dl - z_e
    xsz[lane * 8 + sig] = e + d;                 // zout[c=lane][s=sig]
    double sq = (double)d * (double)d;
#pragma unroll
    for (int off = 1; off < 64; off <<= 1) sq += __shfl_xor(sq, off);
    if (lane == 0) wsq[sig] = sq;

    // support / coeffs: constant-index selection chains only
    if (lane < KS) {
      int   iv = I[0];
      float gv = gam[0];
      if (lane == 1) { iv = I[1]; gv = gam[1]; }
      if (lane == 2) { iv = I[2]; gv = gam[2]; }
      if (lane == 3) { iv = I[3]; gv = gam[3]; }
      if (lane == 4) { iv = I[4]; gv = gam[4]; }
      out[OUT_SUP + (size_t)m * KS + lane] = (float)iv;
      out[OUT_COF + (size_t)m * KS + lane] = gv;
    }
  }

  __syncthreads();
  // coalesced z_dl store from zout (xsz[c*8+s])
  for (int j = t; j < 8 * NC; j += 256) {
    int c = j >> 3, s = j & 7;
    out[zbase + (size_t)c * 4096 + s] = xsz[j];
  }
  if (t == 0) {
    double ssum = 0.0;
#pragma unroll
    for (int i = 0; i < 8; ++i) ssum += wsq[i];
    atomicAdd(accum, ssum);
  }
}

__global__ void final_kernel(const double* __restrict__ accum, float* __restrict__ out) {
  double mse = *accum / 2097152.0;
  out[OUT_LOSS] = (float)(mse + 0.25 * mse);
}

extern "C" void kernel_launch(void* const* d_in, const int* in_sizes, int n_in,
                              void* d_out, int out_size, void* d_ws, size_t ws_size,
                              hipStream_t stream) {
  const float* z_e = (const float*)d_in[0];
  const float* dic = (const float*)d_in[1];
  float* out = (float*)d_out;
  float* ws = (float*)d_ws;
  float* Dn   = ws + WS_DN;
  float* DnT  = ws + WS_DNT;
  float* G    = ws + WS_G;
  double* accu = (double*)(ws + WS_ACCF);

  hipLaunchKernelGGL(norm_kernel,  dim3(8),    dim3(64),  0, stream, dic, Dn, DnT);
  hipLaunchKernelGGL(gram_kernel,  dim3(NA),   dim3(NA),  0, stream, Dn, G, accu);
  hipLaunchKernelGGL(omp_kernel,   dim3(4096), dim3(256), 0, stream,
                     z_e, Dn, DnT, G, out, accu);
  hipLaunchKernelGGL(final_kernel, dim3(1),    dim3(1),   0, stream, accu, out);
}